// Round 8
// baseline (302.357 us; speedup 1.0000x reference)
//
#include <hip/hip_runtime.h>

// y[m,o] = sum_k x[m,k] * (W[o,k] + dW[o,k]) + bias[o],  W int4-dequant.
// M=8192, N=4096(OUT), K=4096(IN).
//
// Round 8: 256x256 GEMM, 16x16x32 f16, WINDOW schedule:
//   K split into 128 sub-tiles of 32-K (32KB LDS each: A 16KB + B 16KB),
//   4 LDS buffers (128KB). Window j = {read tiles 2j,2j+1; stage 2j+2,2j+3;
//   WAITV(0); BAR} -> ONE barrier + ONE vmcnt wait per 64-K of work
//   (vs 4 barriers + 2 waits in r7). Liveness: stage of tile t+2/t+3 targets
//   the buf last read in window j-1 (completed before BAR_{j-1}); residence
//   of next window's tiles guaranteed by per-wave WAITV(0) + BAR_j.
// Tiles remain fragment-packed (r7 format, pack kernels unchanged): a 32-K
// sub-tile = the 8 chunks {rt*2+ks} (stride 2KB) of a 16KB packed tile.
// Frag ds_read_b128 = wave-uniform base + imm + lane*16: conflict-free.

#define M_DIM 8192
#define N_DIM 4096
#define K_DIM 4096
#define NUMEL (N_DIM * K_DIM)

typedef _Float16 half_t;
typedef __attribute__((ext_vector_type(4))) _Float16 half4v;
typedef __attribute__((ext_vector_type(8))) _Float16 half8v;
typedef __attribute__((ext_vector_type(4))) float float4v;
typedef __attribute__((ext_vector_type(4))) int int4v;

#define KTILES 64                // 64-K packed tiles per panel
#define LDT 72                   // fused-fallback padded row stride

static __device__ __forceinline__ void gload16(const void* g, void* l) {
    __builtin_amdgcn_global_load_lds(
        (const __attribute__((address_space(1))) void*)g,
        (__attribute__((address_space(3))) void*)l, 16, 0, 0);
}

// ---------- Phase 1a: dequant+delta -> fp16, fragment-packed (unchanged) ---
__global__ __launch_bounds__(256) void k_pack_w(
    const int* __restrict__ qp, const float* __restrict__ sc,
    const float* __restrict__ zr, const float* __restrict__ dwt,
    unsigned char* __restrict__ Wp)
{
    const size_t o = ((size_t)blockIdx.x * 256 + threadIdx.x) << 4;
    const int chunk16 = (int)(o >> 14);          // panel*64 + kt
    const int c  = (int)(o >> 10) & 15;          // rt*2 + ks
    const int ln = (int)(o >> 4) & 63;
    const int n = (chunk16 >> 6) * 128 + (c >> 1) * 16 + (ln & 15);
    const int k = (chunk16 & 63) * 64 + (c & 1) * 32 + (ln >> 4) * 8;
    const long flat = (long)n * K_DIM + k;
    const int g = n * 32 + (k >> 7);
    const float s = sc[g];
    const float zs = zr[g] * s;
    int4v q4 = *(const int4v*)(qp + (flat >> 1));
    float4v d0 = *(const float4v*)(dwt + flat);
    float4v d1 = *(const float4v*)(dwt + flat + 4);
    float d[8] = {d0[0], d0[1], d0[2], d0[3], d1[0], d1[1], d1[2], d1[3]};
    half8v vh;
#pragma unroll
    for (int j = 0; j < 4; ++j) {
        vh[2*j]   = (half_t)fmaf((float)(q4[j] & 15),        s, d[2*j]   - zs);
        vh[2*j+1] = (half_t)fmaf((float)((q4[j] >> 4) & 15), s, d[2*j+1] - zs);
    }
    *(half8v*)(Wp + o) = vh;
}

// ---------- Phase 1b: x fp32 -> fp16, fragment-packed (unchanged) ----------
__global__ __launch_bounds__(256) void k_pack_x(
    const float* __restrict__ X, unsigned char* __restrict__ Xp)
{
    const size_t o = ((size_t)blockIdx.x * 256 + threadIdx.x) << 4;
    const int chunk16 = (int)(o >> 14);
    const int c  = (int)(o >> 10) & 15;
    const int ln = (int)(o >> 4) & 63;
    const int m = (chunk16 >> 6) * 128 + (c >> 1) * 16 + (ln & 15);
    const int k = (chunk16 & 63) * 64 + (c & 1) * 32 + (ln >> 4) * 8;
    const float* src = X + (size_t)m * K_DIM + k;
    float4v x0 = *(const float4v*)(src);
    float4v x1 = *(const float4v*)(src + 4);
    half8v vh;
    vh[0] = (half_t)x0[0]; vh[1] = (half_t)x0[1];
    vh[2] = (half_t)x0[2]; vh[3] = (half_t)x0[3];
    vh[4] = (half_t)x1[0]; vh[5] = (half_t)x1[1];
    vh[6] = (half_t)x1[2]; vh[7] = (half_t)x1[3];
    *(half8v*)(Xp + o) = vh;
}

// ---------- window-scheduled 256x256 GEMM ----------
#define BARX() do { __builtin_amdgcn_sched_barrier(0); \
                    __builtin_amdgcn_s_barrier(); \
                    __builtin_amdgcn_sched_barrier(0); } while(0)
#define WAITV0() do { __builtin_amdgcn_sched_barrier(0); \
                      asm volatile("s_waitcnt vmcnt(0)" ::: "memory"); \
                      __builtin_amdgcn_sched_barrier(0); } while(0)

// stage one 32-K sub-tile T into buffer BUF (4 gload16/thread)
#define STAGE_TILE(BUF, T) do { \
    const int kt_ = (T) >> 1; \
    const size_t ko_ = ((size_t)kt_ << 14) + (((T) & 1) << 10) + choff; \
    gload16(Apk + apan0 + ko_, &lds[BUF][ldsd]); \
    gload16(Apk + apan1 + ko_, &lds[BUF][ldsd + 8192]); \
    gload16(Bpk + bpan0 + ko_, &lds[BUF][ldsd + 16384]); \
    gload16(Bpk + bpan1 + ko_, &lds[BUF][ldsd + 24576]); \
} while(0)

#define RD_A(BUF, DST, RT0) do { \
_Pragma("unroll") for (int i_ = 0; i_ < 4; ++i_) \
        DST[i_] = *(const half8v*)(&lds[BUF][awm + (((RT0) + i_) << 10) + lane16]); \
} while(0)

#define RD_B(BUF, DST) do { \
_Pragma("unroll") for (int j_ = 0; j_ < 4; ++j_) \
        DST[j_] = *(const half8v*)(&lds[BUF][16384 + bq + (j_ << 10) + lane16]); \
} while(0)

#define MFMA16(A0, AR, BR) do { \
    __builtin_amdgcn_s_setprio(1); \
_Pragma("unroll") for (int i_ = 0; i_ < 4; ++i_) \
_Pragma("unroll") for (int j_ = 0; j_ < 4; ++j_) \
        acc[(A0)+i_][j_] = __builtin_amdgcn_mfma_f32_16x16x32_f16( \
            AR[i_], BR[j_], acc[(A0)+i_][j_], 0, 0, 0); \
    __builtin_amdgcn_s_setprio(0); \
} while(0)

// one window: read tiles TA (buf BA), TA+1 (buf BB); stage TA+2,TA+3
#define WINDOW(BA, BB, TA, STG) do { \
    if (STG) { STAGE_TILE((BA)^2, (TA)+2); STAGE_TILE((BB)^2, (TA)+3); } \
    RD_A(BA, ahA, 0); RD_B(BA, bfA); \
    MFMA16(0, ahA, bfA); \
    RD_A(BA, ah2, 4); \
    MFMA16(4, ah2, bfA); \
    RD_A(BB, ahB, 0); RD_B(BB, bfB); \
    MFMA16(0, ahB, bfB); \
    RD_A(BB, ah2, 4); \
    MFMA16(4, ah2, bfB); \
    WAITV0(); BARX(); \
} while(0)

__global__ __launch_bounds__(512, 2) void k_gemm_win(
    const unsigned char* __restrict__ Apk, const unsigned char* __restrict__ Bpk,
    const float* __restrict__ bias, float* __restrict__ Y)
{
    __shared__ __align__(16) unsigned char lds[4][32768];  // [buf][A 16K | B 16K]

    const int tid  = threadIdx.x;
    const int lane = tid & 63;
    const int wave = tid >> 6;
    const int wm = wave >> 2;              // M half (128 rows)
    const int wn = wave & 3;               // N quarter (64 cols)
    const int awm = wm * 8192;
    const int bq  = (wn >> 1) * 8192 + (wn & 1) * 4096;
    const int lane16 = lane << 4;
    const int ldsd = tid << 4;                               // staging LDS dst
    const size_t choff = ((size_t)(tid >> 6) << 11) + ((tid & 63) << 4);

    const int wg = blockIdx.x;
    const int swg = (wg & 7) * 64 + (wg >> 3);   // 512 blocks, 8 XCDs, bijective
    const int bn = swg & 15;
    const int bm = swg >> 4;

    const size_t apan0 = ((size_t)(2 * bm) * KTILES) << 14;
    const size_t apan1 = ((size_t)(2 * bm + 1) * KTILES) << 14;
    const size_t bpan0 = ((size_t)(2 * bn) * KTILES) << 14;
    const size_t bpan1 = ((size_t)(2 * bn + 1) * KTILES) << 14;

    half8v ahA[4], ahB[4], ah2[4], bfA[4], bfB[4];
    float4v acc[8][4];
    const float4v zero4 = {0.f, 0.f, 0.f, 0.f};
#pragma unroll
    for (int i = 0; i < 8; ++i)
#pragma unroll
        for (int j = 0; j < 4; ++j) acc[i][j] = zero4;

    // ---- prologue: stage tiles 0 (buf0), 1 (buf1) ----
    STAGE_TILE(0, 0); STAGE_TILE(1, 1);
    WAITV0();
    BARX();

    // ---- 31 iterations x 2 windows (tiles 0..123, stages to 125) ----
    for (int it = 0; it < 31; ++it) {
        const int t = it << 2;
        WINDOW(0, 1, t, 1);
        WINDOW(2, 3, t + 2, 1);
    }
    // window 62: tiles 124,125; stage 126,127
    WINDOW(0, 1, 124, 1);
    // window 63: tiles 126,127; no stage
    WINDOW(2, 3, 126, 0);

    // ---- epilogue: 16x16 C/D map col=lane&15, row=(lane>>4)*4+reg ----
    const long m0 = (long)bm * 256 + wm * 128;
    const long n0 = (long)bn * 256 + wn * 64;
#pragma unroll
    for (int mf = 0; mf < 8; ++mf) {
        const long row = m0 + mf * 16 + (lane >> 4) * 4;
#pragma unroll
        for (int nf = 0; nf < 4; ++nf) {
            const long col = n0 + nf * 16 + (lane & 15);
            const float b = bias[col];
#pragma unroll
            for (int r = 0; r < 4; ++r)
                __builtin_nontemporal_store(acc[mf][nf][r] + b,
                                            &Y[(row + r) * N_DIM + col]);
        }
    }
}

// ---------- fallback (no workspace): fused dequant 128x128 GEMM ----------
__global__ __launch_bounds__(256, 2) void k_gemm_fused(
    const float* __restrict__ X, const int* __restrict__ qp,
    const float* __restrict__ sc, const float* __restrict__ zr,
    const float* __restrict__ dwt,
    const float* __restrict__ bias, float* __restrict__ Y)
{
    __shared__ __align__(16) half_t Ah[128 * LDT];
    __shared__ __align__(16) half_t Bh[128 * LDT];

    const int tid  = threadIdx.x;
    const int lane = tid & 63;
    const int wave = tid >> 6;
    const int wm = wave >> 1, wn = wave & 1;
    const int bn = blockIdx.x & 31;
    const int bm = blockIdx.x >> 5;
    const long m0 = (long)bm * 128;
    const long n0 = (long)bn * 128;
    const int fr = lane & 15;
    const int ko = (lane >> 4) * 8;

    const float4v zero4 = {0.f, 0.f, 0.f, 0.f};
    float4v acc[4][4];
#pragma unroll
    for (int i = 0; i < 4; ++i)
#pragma unroll
        for (int j = 0; j < 4; ++j) acc[i][j] = zero4;

    for (int k0 = 0; k0 < K_DIM; k0 += 64) {
        {
            const int ar = tid >> 4;
            const int ac = (tid & 15) * 4;
#pragma unroll
            for (int rr = 0; rr < 8; ++rr) {
                const int row = ar + rr * 16;
                float4v xv = *(const float4v*)(X + (m0 + row) * K_DIM + k0 + ac);
                half4v h;
#pragma unroll
                for (int j = 0; j < 4; ++j) h[j] = (half_t)xv[j];
                *(half4v*)(Ah + row * LDT + ac) = h;
            }
        }
        {
            const int cr = tid >> 3;
            const int cc = (tid & 7) * 8;
#pragma unroll
            for (int rr = 0; rr < 4; ++rr) {
                const int row = cr + rr * 32;
                const long n = n0 + row;
                const int g = (int)(n * 32 + (k0 >> 7));
                const float s = sc[g];
                const float zs = zr[g] * s;
                const long flat = n * K_DIM + k0 + cc;
                int4v q4 = *(const int4v*)(qp + (flat >> 1));
                float4v d0 = *(const float4v*)(dwt + flat);
                float4v d1 = *(const float4v*)(dwt + flat + 4);
                float d[8] = {d0[0], d0[1], d0[2], d0[3], d1[0], d1[1], d1[2], d1[3]};
                half8v vh;
#pragma unroll
                for (int j = 0; j < 4; ++j) {
                    vh[2*j]   = (half_t)fmaf((float)(q4[j] & 15),        s, d[2*j]   - zs);
                    vh[2*j+1] = (half_t)fmaf((float)((q4[j] >> 4) & 15), s, d[2*j+1] - zs);
                }
                *(half8v*)(Bh + row * LDT + cc) = vh;
            }
        }
        __syncthreads();
#pragma unroll
        for (int ks = 0; ks < 2; ++ks) {
            const int kk = ks * 32 + ko;
            half8v a2[4], b2[4];
#pragma unroll
            for (int i = 0; i < 4; ++i) {
                a2[i] = *(const half8v*)(Ah + (wm * 64 + i * 16 + fr) * LDT + kk);
                b2[i] = *(const half8v*)(Bh + (wn * 64 + i * 16 + fr) * LDT + kk);
            }
#pragma unroll
            for (int i = 0; i < 4; ++i)
#pragma unroll
                for (int j = 0; j < 4; ++j)
                    acc[i][j] = __builtin_amdgcn_mfma_f32_16x16x32_f16(
                        a2[i], b2[j], acc[i][j], 0, 0, 0);
        }
        __syncthreads();
    }

#pragma unroll
    for (int i = 0; i < 4; ++i) {
        const long mrow = m0 + wm * 64 + i * 16 + (lane >> 4) * 4;
#pragma unroll
        for (int j = 0; j < 4; ++j) {
            const long col = n0 + wn * 64 + j * 16 + (lane & 15);
            const float b = bias[col];
#pragma unroll
            for (int r = 0; r < 4; ++r)
                Y[(mrow + r) * N_DIM + col] = acc[i][j][r] + b;
        }
    }
}

extern "C" void kernel_launch(void* const* d_in, const int* in_sizes, int n_in,
                              void* d_out, int out_size, void* d_ws, size_t ws_size,
                              hipStream_t stream)
{
    const float* X  = (const float*)d_in[0];
    const int*   qp = (const int*)d_in[1];
    const float* sc = (const float*)d_in[2];
    const float* zr = (const float*)d_in[3];
    const float* dwt = (const float*)d_in[4];
    const float* bs = (const float*)d_in[5];
    float* Y = (float*)d_out;

    const size_t needB = (size_t)N_DIM * K_DIM * 2;   // 33.5 MB
    const size_t needA = (size_t)M_DIM * K_DIM * 2;   // 67.1 MB

    if (ws_size >= needA + needB) {
        unsigned char* Bpk = (unsigned char*)d_ws;
        unsigned char* Apk = Bpk + needB;
        k_pack_w<<<dim3((unsigned)(needB >> 12)), dim3(256), 0, stream>>>(qp, sc, zr, dwt, Bpk);
        k_pack_x<<<dim3((unsigned)(needA >> 12)), dim3(256), 0, stream>>>(X, Apk);
        k_gemm_win<<<dim3((M_DIM / 256) * (N_DIM / 256)), dim3(512), 0, stream>>>(Apk, Bpk, bs, Y);
    } else {
        k_gemm_fused<<<dim3((M_DIM / 128) * (N_DIM / 128)), dim3(256), 0, stream>>>(
            X, qp, sc, zr, dwt, bs, Y);
    }
}